// Round 1
// 61.572 us; speedup vs baseline: 2.7828x; 2.7828x over previous
//
#include <hip/hip_runtime.h>
#include <math.h>

#define VOCAB 100000
#define BATCH 4096
#define DOC_LEN 200
#define EMBED_DIM 300
#define NUM_CLASSES 20

// ---------------------------------------------------------------------------
// Kernel 1:  P[v][c] = (1/DOC_LEN) * sum_k emb[v][k] * W[c][k]
// One streaming pass over the 120 MB table; W transposed in LDS, read as
// wave-uniform b128 broadcasts. 2 rows/thread amortizes the DS reads.
// ---------------------------------------------------------------------------
#define K1_BLOCK 128
#define K1_ROWS  256   // rows per block (2 per thread)

__global__ __launch_bounds__(K1_BLOCK) void project_kernel(
    const float* __restrict__ emb,   // (VOCAB, 300)
    const float* __restrict__ W,     // (20, 300)
    float*       __restrict__ P)     // (VOCAB, 20)  [workspace]
{
    __shared__ float sWT[EMBED_DIM][NUM_CLASSES];   // 24000 B, W transposed

    for (int i = threadIdx.x; i < NUM_CLASSES * EMBED_DIM; i += K1_BLOCK) {
        const int c = i / EMBED_DIM;
        const int k = i % EMBED_DIM;
        sWT[k][c] = W[i];
    }
    __syncthreads();

    const int row0 = blockIdx.x * K1_ROWS + threadIdx.x;
    const int row1 = row0 + K1_BLOCK;
    const float* e0 = emb + (size_t)(row0 < VOCAB ? row0 : VOCAB - 1) * EMBED_DIM;
    const float* e1 = emb + (size_t)(row1 < VOCAB ? row1 : VOCAB - 1) * EMBED_DIM;

    float acc0[NUM_CLASSES], acc1[NUM_CLASSES];
    #pragma unroll
    for (int c = 0; c < NUM_CLASSES; ++c) { acc0[c] = 0.0f; acc1[c] = 0.0f; }

    // 300 = 25 chunks of 12 floats (3 x float4 per row -> 6 loads in flight)
    for (int k = 0; k < EMBED_DIM; k += 12) {
        float4 a[3], b[3];
        #pragma unroll
        for (int j = 0; j < 3; ++j) {
            a[j] = *reinterpret_cast<const float4*>(e0 + k + 4 * j);
            b[j] = *reinterpret_cast<const float4*>(e1 + k + 4 * j);
        }
        #pragma unroll
        for (int j = 0; j < 3; ++j) {
            #pragma unroll
            for (int kk = 0; kk < 4; ++kk) {
                const float av = (&a[j].x)[kk];
                const float bv = (&b[j].x)[kk];
                const int   kw = k + 4 * j + kk;
                #pragma unroll
                for (int c4 = 0; c4 < NUM_CLASSES; c4 += 4) {
                    const float4 w = *reinterpret_cast<const float4*>(&sWT[kw][c4]);
                    acc0[c4 + 0] += av * w.x;  acc0[c4 + 1] += av * w.y;
                    acc0[c4 + 2] += av * w.z;  acc0[c4 + 3] += av * w.w;
                    acc1[c4 + 0] += bv * w.x;  acc1[c4 + 1] += bv * w.y;
                    acc1[c4 + 2] += bv * w.z;  acc1[c4 + 3] += bv * w.w;
                }
            }
        }
    }

    const float inv = 1.0f / (float)DOC_LEN;   // fold mean into P
    if (row0 < VOCAB) {
        float* p = P + (size_t)row0 * NUM_CLASSES;
        #pragma unroll
        for (int c4 = 0; c4 < NUM_CLASSES; c4 += 4) {
            const float4 v = make_float4(acc0[c4] * inv, acc0[c4 + 1] * inv,
                                         acc0[c4 + 2] * inv, acc0[c4 + 3] * inv);
            *reinterpret_cast<float4*>(p + c4) = v;
        }
    }
    if (row1 < VOCAB) {
        float* p = P + (size_t)row1 * NUM_CLASSES;
        #pragma unroll
        for (int c4 = 0; c4 < NUM_CLASSES; c4 += 4) {
            const float4 v = make_float4(acc1[c4] * inv, acc1[c4 + 1] * inv,
                                         acc1[c4 + 2] * inv, acc1[c4 + 3] * inv);
            *reinterpret_cast<float4*>(p + c4) = v;
        }
    }
}

// ---------------------------------------------------------------------------
// Kernel 2: out[doc] = softmax( sum_l P[x[doc][l]] + b )
// One wave per doc. 64 lanes = 3 position-groups x 20 classes (4 idle).
// Lane (g,c) accumulates class c over positions l = g, g+3, ...
// ---------------------------------------------------------------------------
#define K2_BLOCK 256
#define DOCS_PER_BLOCK 4

__global__ __launch_bounds__(K2_BLOCK) void pool_softmax_kernel(
    const float* __restrict__ P,     // (VOCAB, 20), pre-scaled by 1/DOC_LEN
    const float* __restrict__ bias,  // (20,)
    const int*   __restrict__ x,     // (BATCH, 200)
    float*       __restrict__ out)   // (BATCH, 20)
{
    __shared__ int sidx[DOCS_PER_BLOCK][DOC_LEN];

    const int doc0 = blockIdx.x * DOCS_PER_BLOCK;
    const int tid  = threadIdx.x;

    for (int i = tid; i < DOCS_PER_BLOCK * DOC_LEN; i += K2_BLOCK)
        (&sidx[0][0])[i] = x[doc0 * DOC_LEN + i];
    __syncthreads();

    const int wave = tid >> 6;
    const int lane = tid & 63;
    const int doc  = doc0 + wave;
    const int g    = lane / NUM_CLASSES;          // 0..2 active, 3 idle
    const int c    = lane - g * NUM_CLASSES;

    float acc = 0.0f;
    if (g < 3) {
        #pragma unroll 4
        for (int l = g; l < DOC_LEN; l += 3) {
            const int row = sidx[wave][l];        // LDS broadcast per group
            acc += P[(size_t)row * NUM_CLASSES + c];
        }
    }

    // combine the 3 position-groups: lane c needs lanes c, c+20, c+40
    const float a1 = __shfl(acc, lane + 20, 64);
    const float a2 = __shfl(acc, lane + 40, 64);

    float v = (lane < NUM_CLASSES) ? (acc + a1 + a2 + bias[c]) : -INFINITY;

    // softmax across lanes 0..19 (reduce within width-32 group)
    float m = v;
    #pragma unroll
    for (int off = 16; off > 0; off >>= 1)
        m = fmaxf(m, __shfl_xor(m, off, 32));
    const float e = (lane < NUM_CLASSES) ? expf(v - m) : 0.0f;
    float s = e;
    #pragma unroll
    for (int off = 16; off > 0; off >>= 1)
        s += __shfl_xor(s, off, 32);

    if (lane < NUM_CLASSES)
        out[doc * NUM_CLASSES + lane] = e / s;
}

extern "C" void kernel_launch(void* const* d_in, const int* in_sizes, int n_in,
                              void* d_out, int out_size, void* d_ws, size_t ws_size,
                              hipStream_t stream) {
    const float* emb  = (const float*)d_in[0];
    const float* W    = (const float*)d_in[1];
    const float* bias = (const float*)d_in[2];
    const int*   x    = (const int*)d_in[3];
    float* out = (float*)d_out;
    float* P   = (float*)d_ws;   // needs VOCAB*20*4 = 8,000,000 B

    project_kernel<<<(VOCAB + K1_ROWS - 1) / K1_ROWS, K1_BLOCK, 0, stream>>>(emb, W, P);
    pool_softmax_kernel<<<BATCH / DOCS_PER_BLOCK, K2_BLOCK, 0, stream>>>(P, bias, x, out);
}